// Round 14
// baseline (1543.990 us; speedup 1.0000x reference)
//
#include <hip/hip_runtime.h>
#include <cstdint>
#include <cstddef>

#define DEV static __device__ __forceinline__

typedef unsigned short u16;
typedef unsigned int u32;
typedef __attribute__((ext_vector_type(8))) short short8;
typedef __attribute__((ext_vector_type(8))) __bf16 bf16x8;
typedef __attribute__((ext_vector_type(4))) float f32x4;

constexpr size_t PER_D = 1474560;

DEV u16 f2bf(float f) {
  u32 u = __builtin_bit_cast(u32, f);
  u32 r = (u + 0x7fffu + ((u >> 16) & 1u)) >> 16;
  return (u16)r;
}
DEV float bf2f(u16 h) { u32 u = ((u32)h) << 16; return __builtin_bit_cast(float, u); }
DEV u32 pack2(float a, float b) { return (u32)f2bf(a) | ((u32)f2bf(b) << 16); }

// async global->LDS, 16B per lane; lds base must be wave-uniform (dest = base + lane*16)
DEV void ld_lds16(const u16* g, u16* l) {
  __builtin_amdgcn_global_load_lds((const __attribute__((address_space(1))) void*)g,
                                   (__attribute__((address_space(3))) void*)l, 16, 0, 0);
}

// ---------------- all weight transposes+casts in ONE dispatch ----------------
__global__ __launch_bounds__(256) void k_tcast_all(const float* __restrict__ pw, const float* __restrict__ wi,
                                                   const float* __restrict__ wg, const float* __restrict__ w1,
                                                   const float* __restrict__ w2, u16* __restrict__ patchT,
                                                   u16* __restrict__ ugT0, u16* __restrict__ w1T0,
                                                   u16* __restrict__ w2T0) {
  __shared__ float tl[32][33];
  int g = blockIdx.x;
  const float* src; u16* dst; int K, N, bx, by;
  if (g < 288) {                       // patch_w (768,384)
    src = pw; dst = patchT; K = 768; N = 384; bx = g % 12; by = g / 12;
  } else if (g < 288 + 1728) {         // w_in (12,384,384)
    int l = g - 288, z = l / 144, r = l - z * 144;
    bx = r % 12; by = r / 12; K = 384; N = 384;
    src = wi + (size_t)z * 147456; dst = ugT0 + (size_t)z * PER_D;
  } else if (g < 288 + 3456) {         // w_g (12,384,384)
    int l = g - 288 - 1728, z = l / 144, r = l - z * 144;
    bx = r % 12; by = r / 12; K = 384; N = 384;
    src = wg + (size_t)z * 147456; dst = ugT0 + (size_t)z * PER_D + 147456;
  } else if (g < 288 + 3456 + 6912) {  // w1 (12,384,1536)
    int l = g - 288 - 3456, z = l / 576, r = l - z * 576;
    bx = r % 48; by = r / 48; K = 384; N = 1536;
    src = w1 + (size_t)z * 589824; dst = w1T0 + (size_t)z * PER_D;
  } else {                             // w2 (12,1536,384)
    int l = g - 288 - 3456 - 6912, z = l / 576, r = l - z * 576;
    bx = r % 12; by = r / 12; K = 1536; N = 384;
    src = w2 + (size_t)z * 589824; dst = w2T0 + (size_t)z * PER_D;
  }
  int tx = threadIdx.x, ty = threadIdx.y;
  int n0 = bx * 32, k0 = by * 32;
#pragma unroll
  for (int i = 0; i < 4; ++i)
    tl[ty + i * 8][tx] = src[(size_t)(k0 + ty + i * 8) * N + n0 + tx];
  __syncthreads();
#pragma unroll
  for (int i = 0; i < 4; ++i)
    dst[(size_t)(n0 + ty + i * 8) * K + k0 + tx] = f2bf(tl[tx][ty + i * 8]);
}

// ---------------- fp32 transpose with N-guard: src (K,N) -> dst (N,K); K % 32 == 0 ----------------
__global__ __launch_bounds__(256) void k_tcastf(const float* __restrict__ src, float* __restrict__ dst,
                                                int K, int N) {
  __shared__ float tl[32][33];
  int tx = threadIdx.x, ty = threadIdx.y;
  int n0 = blockIdx.x * 32, k0 = blockIdx.y * 32;
#pragma unroll
  for (int i = 0; i < 4; ++i)
    if (n0 + tx < N) tl[ty + i * 8][tx] = src[(size_t)(k0 + ty + i * 8) * N + n0 + tx];
  __syncthreads();
#pragma unroll
  for (int i = 0; i < 4; ++i)
    if (n0 + ty + i * 8 < N) dst[(size_t)(n0 + ty + i * 8) * K + k0 + tx] = tl[tx][ty + i * 8];
}

// ---------------- patch extraction: x (B,224,224,3) -> pA bf16 (6272,768); 8 elems/thread ----------------
__global__ __launch_bounds__(256) void k_patch_extract(const float* __restrict__ x, u16* __restrict__ pA) {
  int idx = (blockIdx.x * 256 + threadIdx.x) * 8;
  int token = idx / 768, kk = idx - token * 768;
  int b = token / 196, t = token - b * 196;
  int gy = t / 14, gx = t - gy * 14;
  int py = kk / 48, rem = kk - py * 48;
  int px = rem / 3, ch = rem - px * 3;
  size_t s = ((size_t)(b * 224 + gy * 16 + py) * 224 + (gx * 16 + px)) * 3 + ch;
  union { short8 s8; u16 u[8]; } pk;
#pragma unroll
  for (int j = 0; j < 8; ++j) pk.u[j] = f2bf(x[s + j]);
  *(short8*)(pA + idx) = pk.s8;
}

// ---------------- LayerNorm: h fp32 (6272,384) -> z bf16; wave/token, lane-contiguous ----------------
__global__ __launch_bounds__(256) void k_ln(const float* __restrict__ h, u16* __restrict__ z,
                                            const float* __restrict__ sc, const float* __restrict__ bi) {
  int wave = threadIdx.x >> 6, lane = threadIdx.x & 63;
  int token = blockIdx.x * 4 + wave;
  const float* hp = h + (size_t)token * 384 + lane * 6;
  float2 v0 = *(const float2*)hp;
  float2 v1 = *(const float2*)(hp + 2);
  float2 v2 = *(const float2*)(hp + 4);
  float sum = v0.x + v0.y + v1.x + v1.y + v2.x + v2.y;
  float sq = v0.x * v0.x + v0.y * v0.y + v1.x * v1.x + v1.y * v1.y + v2.x * v2.x + v2.y * v2.y;
#pragma unroll
  for (int o = 1; o < 64; o <<= 1) { sum += __shfl_xor(sum, o); sq += __shfl_xor(sq, o); }
  float mean = sum * (1.f / 384.f);
  float var = sq * (1.f / 384.f) - mean * mean;
  float rstd = rsqrtf(var + 1e-6f);
  const float* scp = sc + lane * 6;
  const float* bip = bi + lane * 6;
  float2 s0 = *(const float2*)scp, s1 = *(const float2*)(scp + 2), s2 = *(const float2*)(scp + 4);
  float2 b0 = *(const float2*)bip, b1 = *(const float2*)(bip + 2), b2 = *(const float2*)(bip + 4);
  u16* zp = z + (size_t)token * 384 + lane * 6;
  *(u32*)(zp)     = pack2((v0.x - mean) * rstd * s0.x + b0.x, (v0.y - mean) * rstd * s0.y + b0.y);
  *(u32*)(zp + 2) = pack2((v1.x - mean) * rstd * s1.x + b1.x, (v1.y - mean) * rstd * s1.y + b1.y);
  *(u32*)(zp + 4) = pack2((v2.x - mean) * rstd * s2.x + b2.x, (v2.y - mean) * rstd * s2.y + b2.y);
}

// ---------------- GEMM (N-tiled): C = A * BT, 64x128 tile, PANELS*32-deep K chunks ----------------
// MODE 1: n<384 -> outb = bf16(acc+bias0[n]); else outb2 = bf16(sigmoid(acc+bias1[n-384]))  (u,g)
// MODE 2: outb bf16 = gelu_tanh(acc + bias0[n]), row stride N      (MLP1)
template <int MODE, int PANELS>
__global__ __launch_bounds__(256) void k_gemm(const u16* __restrict__ A, const u16* __restrict__ BT,
                                              int K, int N,
                                              const float* __restrict__ bias0, const float* __restrict__ bias1,
                                              u16* __restrict__ outb, u16* __restrict__ outb2) {
  __shared__ alignas(16) u16 As[PANELS][64 * 32];
  __shared__ alignas(16) u16 Bs[PANELS][128 * 32];
  const int tid = threadIdx.x;
  const int tm = blockIdx.y * 64, tn = blockIdx.x * 128;
  const int lane = tid & 63, wave = tid >> 6;
  const int wy = (wave >> 1) * 32, wx = (wave & 1) * 64;
  const int quad = lane >> 4, r15 = lane & 15;
  const int swz = (quad ^ ((r15 >> 1) & 3)) * 8;
  const int rowS = tid >> 2;
  const int colS = (((tid & 3) ^ ((rowS >> 1) & 3))) * 8;
  const u16* Ab = A + (size_t)(tm + rowS) * K + colS;
  const u16* Bb = BT + (size_t)(tn + rowS) * K + colS;
  f32x4 acc[2][4] = {};
  for (int k0 = 0; k0 < K; k0 += PANELS * 32) {
#pragma unroll
    for (int p = 0; p < PANELS; ++p) {
      ld_lds16(Ab + k0 + p * 32, &As[p][wave * 512]);
      ld_lds16(Bb + k0 + p * 32, &Bs[p][wave * 512]);
      ld_lds16(Bb + (size_t)64 * K + k0 + p * 32, &Bs[p][wave * 512 + 2048]);
    }
    __syncthreads();
#pragma unroll
    for (int p = 0; p < PANELS; ++p) {
      bf16x8 af[2], bw[4];
#pragma unroll
      for (int i = 0; i < 2; ++i) af[i] = *(const bf16x8*)&As[p][(wy + i * 16 + r15) * 32 + swz];
#pragma unroll
      for (int j = 0; j < 4; ++j) bw[j] = *(const bf16x8*)&Bs[p][(wx + j * 16 + r15) * 32 + swz];
#pragma unroll
      for (int i = 0; i < 2; ++i)
#pragma unroll
        for (int j = 0; j < 4; ++j)
          acc[i][j] = __builtin_amdgcn_mfma_f32_16x16x32_bf16(af[i], bw[j], acc[i][j], 0, 0, 0);
    }
    __syncthreads();
  }
#pragma unroll
  for (int i = 0; i < 2; ++i) {
#pragma unroll
    for (int j = 0; j < 4; ++j) {
#pragma unroll
      for (int rr = 0; rr < 4; ++rr) {
        int m = tm + wy + i * 16 + quad * 4 + rr;
        int n = tn + wx + j * 16 + r15;
        float v = acc[i][j][rr];
        if (MODE == 1) {
          if (n < 384) {
            outb[(size_t)m * 384 + n] = f2bf(v + bias0[n]);
          } else {
            float t = v + bias1[n - 384];
            outb2[(size_t)m * 384 + (n - 384)] = f2bf(1.f / (1.f + expf(-t)));
          }
        } else {
          v += bias0[n];
          float gl = 0.5f * v * (1.f + tanhf(0.7978845608028654f * (v + 0.044715f * v * v * v)));
          outb[(size_t)m * N + n] = f2bf(gl);
        }
      }
    }
  }
}

// ---------------- full-width GEMM (N=384) + residual + fused next-LN ----------------
// 32x384 tile, 196 blocks (one round on 256 CUs), one block owns complete rows ->
// LN of the RESULT fuses in-epilogue (no refetch): write h fp32 AND z bf16.
// MODE 0: v = acc + bias0[n] + res[(m%196)*384+n]   (patch embed + pos)
// MODE 3: v = res[m*384+n] + acc + bias0[n]         (MLP2 + residual)
// if (sc): z[m*384+n] = bf16((v-mean_row)*rstd_row*sc[n]+bi[n])
template <int MODE>
__global__ __launch_bounds__(256) void k_gemm_nfull(const u16* __restrict__ A, const u16* __restrict__ BT,
                                                    int K, const float* __restrict__ bias0,
                                                    float* __restrict__ out0, const float* __restrict__ res,
                                                    const float* __restrict__ sc, const float* __restrict__ bi,
                                                    u16* __restrict__ zout) {
  __shared__ alignas(16) u16 As[2][32 * 32];   // 2 x 2 KB
  __shared__ alignas(16) u16 Bs[2][384 * 32];  // 2 x 24 KB
  __shared__ float st[2][32][4];
  const int tid = threadIdx.x;
  const int tm = blockIdx.x * 32;
  const int lane = tid & 63, wave = tid >> 6;
  const int quad = lane >> 4, r15 = lane & 15;
  const int swz = (quad ^ ((r15 >> 1) & 3)) * 8;
  const int rowS = tid >> 2;
  const int colS = (((tid & 3) ^ ((rowS >> 1) & 3))) * 8;
  const u16* Ab = A + (size_t)(tm + (rowS & 31)) * K + colS;
  const u16* Bb = BT + (size_t)rowS * K + colS;
  f32x4 acc[2][6] = {};
  for (int k0 = 0; k0 < K; k0 += 64) {
#pragma unroll
    for (int p = 0; p < 2; ++p) {
      if (tid < 128) ld_lds16(Ab + k0 + p * 32, &As[p][wave * 512]);  // wave-uniform guard
#pragma unroll
      for (int s6 = 0; s6 < 6; ++s6)
        ld_lds16(Bb + (size_t)s6 * 64 * K + k0 + p * 32, &Bs[p][wave * 512 + s6 * 2048]);
    }
    __syncthreads();
#pragma unroll
    for (int p = 0; p < 2; ++p) {
      bf16x8 af[2], bw[6];
#pragma unroll
      for (int i = 0; i < 2; ++i) af[i] = *(const bf16x8*)&As[p][(i * 16 + r15) * 32 + swz];
#pragma unroll
      for (int j = 0; j < 6; ++j) bw[j] = *(const bf16x8*)&Bs[p][(wave * 96 + j * 16 + r15) * 32 + swz];
#pragma unroll
      for (int i = 0; i < 2; ++i)
#pragma unroll
        for (int j = 0; j < 6; ++j)
          acc[i][j] = __builtin_amdgcn_mfma_f32_16x16x32_bf16(af[i], bw[j], acc[i][j], 0, 0, 0);
    }
    __syncthreads();
  }
  // epilogue: v = res + acc + bias; write h; keep v in acc for LN
#pragma unroll
  for (int i = 0; i < 2; ++i)
#pragma unroll
    for (int j = 0; j < 6; ++j)
#pragma unroll
      for (int rr = 0; rr < 4; ++rr) {
        int m = tm + i * 16 + quad * 4 + rr;
        int n = wave * 96 + j * 16 + r15;
        float v = acc[i][j][rr] + bias0[n];
        if (MODE == 0) v += res[(size_t)(m % 196) * 384 + n];
        else v += res[(size_t)m * 384 + n];
        out0[(size_t)m * 384 + n] = v;
        acc[i][j][rr] = v;
      }
  if (sc) {  // fused next-LN: block owns full rows
#pragma unroll
    for (int i = 0; i < 2; ++i)
#pragma unroll
      for (int rr = 0; rr < 4; ++rr) {
        float s = 0.f, s2 = 0.f;
#pragma unroll
        for (int j = 0; j < 6; ++j) {
          float v = acc[i][j][rr];
          s += v; s2 += v * v;
        }
#pragma unroll
        for (int o = 1; o < 16; o <<= 1) { s += __shfl_xor(s, o); s2 += __shfl_xor(s2, o); }
        if (r15 == 0) {
          int row = i * 16 + quad * 4 + rr;
          st[0][row][wave] = s;
          st[1][row][wave] = s2;
        }
      }
    __syncthreads();
#pragma unroll
    for (int i = 0; i < 2; ++i)
#pragma unroll
      for (int rr = 0; rr < 4; ++rr) {
        int row = i * 16 + quad * 4 + rr;
        float tot = st[0][row][0] + st[0][row][1] + st[0][row][2] + st[0][row][3];
        float tot2 = st[1][row][0] + st[1][row][1] + st[1][row][2] + st[1][row][3];
        float mean = tot * (1.f / 384.f);
        float rstd = rsqrtf(tot2 * (1.f / 384.f) - mean * mean + 1e-6f);
        size_t mb = (size_t)(tm + row) * 384;
#pragma unroll
        for (int j = 0; j < 6; ++j) {
          int n = wave * 96 + j * 16 + r15;
          zout[mb + n] = f2bf((acc[i][j][rr] - mean) * rstd * sc[n] + bi[n]);
        }
      }
  }
}

// ---------------- gated depthwise-conv recurrence, T=8; ping-pong LDS, 9 barriers ----------------
__global__ __launch_bounds__(256) void k_recur(float* __restrict__ h, const u16* __restrict__ ubuf,
                                               const u16* __restrict__ gbuf, const float* __restrict__ kd) {
  __shared__ float sb[2][16 * 16 * 8];  // [buf][y+1][x+1][c], zero halo, 16 KB
  const int tid = threadIdx.x;
  const int b = blockIdx.x, cg = blockIdx.y;
  const int c = tid & 7, pg = tid >> 3;  // pg in [0,32)
  const int cfull = cg * 8 + c;
  float kw[9];
#pragma unroll
  for (int q = 0; q < 9; ++q) kw[q] = kd[q * 384 + cfull];
  float gr[7], ur[7], sr[7];
  int yy[7], xx[7];
#pragma unroll
  for (int kk = 0; kk < 7; ++kk) {
    int p = pg + kk * 32;
    bool ok = p < 196;
    size_t a = (size_t)(b * 196 + (ok ? p : 0)) * 384 + cfull;
    gr[kk] = ok ? bf2f(gbuf[a]) : 0.f;
    ur[kk] = ok ? bf2f(ubuf[a]) : 0.f;
    sr[kk] = 0.f;
    yy[kk] = p / 14; xx[kk] = p - yy[kk] * 14;
  }
  for (int i = tid; i < 2 * 16 * 16 * 8; i += 256) ((float*)sb)[i] = 0.f;
  __syncthreads();
#pragma unroll
  for (int kk = 0; kk < 7; ++kk) {
    int p = pg + kk * 32;
    if (p < 196) {
      sr[kk] = (1.f - gr[kk]) * ur[kk];
      sb[0][((yy[kk] + 1) * 16 + (xx[kk] + 1)) * 8 + c] = sr[kk];
    }
  }
  __syncthreads();
  for (int t = 1; t < 8; ++t) {
    const float* rd = sb[(t - 1) & 1];
    float* wr = sb[t & 1];
#pragma unroll
    for (int kk = 0; kk < 7; ++kk) {
      int p = pg + kk * 32;
      if (p < 196) {
        int base = (yy[kk] * 16 + xx[kk]) * 8 + c;
        float conv = 0.f;
#pragma unroll
        for (int dy = 0; dy < 3; ++dy)
#pragma unroll
          for (int dx = 0; dx < 3; ++dx)
            conv += kw[dy * 3 + dx] * rd[base + (dy * 16 + dx) * 8];
        sr[kk] = gr[kk] * conv + (1.f - gr[kk]) * ur[kk];
        wr[((yy[kk] + 1) * 16 + (xx[kk] + 1)) * 8 + c] = sr[kk];
      }
    }
    __syncthreads();
  }
#pragma unroll
  for (int kk = 0; kk < 7; ++kk) {
    int p = pg + kk * 32;
    if (p < 196) {
      size_t a = (size_t)(b * 196 + p) * 384 + cfull;
      h[a] += sr[kk];
    }
  }
}

// ---------------- fused final LN + spatial max-pool: pooled(32,384) fp32 ----------------
__global__ __launch_bounds__(256) void k_lnpool(const float* __restrict__ h, const float* __restrict__ sc,
                                                const float* __restrict__ bi, float* __restrict__ pooled) {
  __shared__ float red[4][384];
  const int b = blockIdx.x;
  const int wave = threadIdx.x >> 6, lane = threadIdx.x & 63;
  const float* scp = sc + lane * 6;
  const float* bip = bi + lane * 6;
  float2 s0 = *(const float2*)scp, s1 = *(const float2*)(scp + 2), s2 = *(const float2*)(scp + 4);
  float2 b0 = *(const float2*)bip, b1 = *(const float2*)(bip + 2), b2 = *(const float2*)(bip + 4);
  float mx[6] = {-3.4e38f, -3.4e38f, -3.4e38f, -3.4e38f, -3.4e38f, -3.4e38f};
  for (int i = 0; i < 49; ++i) {
    int t = wave + 4 * i;
    const float* hp = h + (size_t)(b * 196 + t) * 384 + lane * 6;
    float2 v0 = *(const float2*)hp;
    float2 v1 = *(const float2*)(hp + 2);
    float2 v2 = *(const float2*)(hp + 4);
    float sum = v0.x + v0.y + v1.x + v1.y + v2.x + v2.y;
    float sq = v0.x * v0.x + v0.y * v0.y + v1.x * v1.x + v1.y * v1.y + v2.x * v2.x + v2.y * v2.y;
#pragma unroll
    for (int o = 1; o < 64; o <<= 1) { sum += __shfl_xor(sum, o); sq += __shfl_xor(sq, o); }
    float mean = sum * (1.f / 384.f);
    float var = sq * (1.f / 384.f) - mean * mean;
    float rstd = rsqrtf(var + 1e-6f);
    mx[0] = fmaxf(mx[0], (v0.x - mean) * rstd * s0.x + b0.x);
    mx[1] = fmaxf(mx[1], (v0.y - mean) * rstd * s0.y + b0.y);
    mx[2] = fmaxf(mx[2], (v1.x - mean) * rstd * s1.x + b1.x);
    mx[3] = fmaxf(mx[3], (v1.y - mean) * rstd * s1.y + b1.y);
    mx[4] = fmaxf(mx[4], (v2.x - mean) * rstd * s2.x + b2.x);
    mx[5] = fmaxf(mx[5], (v2.y - mean) * rstd * s2.y + b2.y);
  }
#pragma unroll
  for (int j = 0; j < 6; ++j) red[wave][lane * 6 + j] = mx[j];
  __syncthreads();
  if (wave == 0) {
#pragma unroll
    for (int j = 0; j < 6; ++j) {
      int cc = lane * 6 + j;
      pooled[b * 384 + cc] = fmaxf(fmaxf(red[0][cc], red[1][cc]), fmaxf(red[2][cc], red[3][cc]));
    }
  }
}

// ---------------- head GEMV: wave per (b,n); hwT is (1000,384) fp32 ----------------
__global__ __launch_bounds__(256) void k_head(const float* __restrict__ pooled, const float* __restrict__ hwT,
                                              const float* __restrict__ hb, float* __restrict__ out) {
  int w = (blockIdx.x * 256 + threadIdx.x) >> 6;  // 0..31999
  int lane = threadIdx.x & 63;
  int b = w / 1000, n = w - b * 1000;
  const float* pp = pooled + b * 384 + lane;
  const float* wp = hwT + (size_t)n * 384 + lane;
  float acc = 0.f;
#pragma unroll
  for (int j = 0; j < 6; ++j) acc += pp[j * 64] * wp[j * 64];
#pragma unroll
  for (int o = 1; o < 64; o <<= 1) acc += __shfl_xor(acc, o);
  if (lane == 0) out[w] = acc + hb[n];
}

extern "C" void kernel_launch(void* const* d_in, const int* in_sizes, int n_in,
                              void* d_out, int out_size, void* d_ws, size_t ws_size,
                              hipStream_t stream) {
  const float* x       = (const float*)d_in[0];
  const float* patch_w = (const float*)d_in[1];
  const float* patch_b = (const float*)d_in[2];
  const float* pos     = (const float*)d_in[3];
  const float* ln1_s   = (const float*)d_in[4];
  const float* ln1_b   = (const float*)d_in[5];
  const float* w_in    = (const float*)d_in[6];
  const float* b_in    = (const float*)d_in[7];
  const float* w_g     = (const float*)d_in[8];
  const float* b_g     = (const float*)d_in[9];
  const float* k_dw    = (const float*)d_in[10];
  const float* ln2_s   = (const float*)d_in[11];
  const float* ln2_b   = (const float*)d_in[12];
  const float* w1      = (const float*)d_in[13];
  const float* b1      = (const float*)d_in[14];
  const float* w2      = (const float*)d_in[15];
  const float* b2      = (const float*)d_in[16];
  const float* lnf_s   = (const float*)d_in[17];
  const float* lnf_b   = (const float*)d_in[18];
  const float* head_w  = (const float*)d_in[19];
  const float* head_b  = (const float*)d_in[20];
  float* out = (float*)d_out;

  const size_t M = 6272;
  const size_t SZ_TOK = M * 384;               // 2408448
  const size_t SZ_HID = M * 1536;              // 9633792
  const size_t WT_ELEMS = 17989632;            // patchT + 12*(ugT + w1T + w2T)
  const size_t NEED = SZ_TOK * 4 + SZ_TOK * 2 * 3 + SZ_HID * 2 + WT_ELEMS * 2;
  if (ws_size < NEED) return;

  char* ws = (char*)d_ws;
  float* h = (float*)ws;   ws += SZ_TOK * 4;
  u16* ub  = (u16*)ws;     ws += SZ_TOK * 2;
  u16* gb  = (u16*)ws;     ws += SZ_TOK * 2;
  u16* z   = (u16*)ws;     ws += SZ_TOK * 2;
  u16* hid = (u16*)ws;     ws += SZ_HID * 2;
  u16* pA  = hid;          // alias: patch A-matrix (M*768) fits in hid (M*1536), used before hid
  u16* wT  = (u16*)ws;
  float* pooled = (float*)ub;  // reuse ub at the end (free after last recur)
  float* hwT = (float*)hid;    // reuse hid at the end (free after last gemm3)

  // wT layout (elems): patchT[294912]; per d: WiT[147456] WgT[147456] w1T[589824] w2T[589824]
  u16* patchT = wT;
  u16* ugT0 = wT + 294912;
  u16* w1T0 = wT + 294912 + 294912;
  u16* w2T0 = wT + 294912 + 294912 + 589824;

  dim3 tb(32, 8);
  k_tcast_all<<<17568, tb, 0, stream>>>(patch_w, w_in, w_g, w1, w2, patchT, ugT0, w1T0, w2T0);

  k_patch_extract<<<2352, 256, 0, stream>>>(x, pA);

  // patch embed GEMM + pos + fused ln1(d=0): h, z
  k_gemm_nfull<0><<<196, 256, 0, stream>>>(pA, patchT, 768, patch_b, h, pos,
                                           ln1_s, ln1_b, z);

  for (int d = 0; d < 12; ++d) {
    const u16* ugT = ugT0 + (size_t)d * PER_D;
    const u16* w1T = w1T0 + (size_t)d * PER_D;
    const u16* w2T = w2T0 + (size_t)d * PER_D;
    k_gemm<1, 2><<<dim3(6, 98), 256, 0, stream>>>(z, ugT, 384, 768, b_in + (size_t)d * 384,
                                                  b_g + (size_t)d * 384, ub, gb);
    k_recur<<<dim3(32, 48), 256, 0, stream>>>(h, ub, gb, k_dw + (size_t)d * 3456);
    k_ln<<<1568, 256, 0, stream>>>(h, z, ln2_s + (size_t)d * 384, ln2_b + (size_t)d * 384);
    k_gemm<2, 2><<<dim3(12, 98), 256, 0, stream>>>(z, w1T, 384, 1536, b1 + (size_t)d * 1536,
                                                   nullptr, hid, nullptr);
    // MLP2 + residual + fused ln1(d+1) (skip z-write on last layer)
    const float* scN = (d < 11) ? ln1_s + (size_t)(d + 1) * 384 : nullptr;
    const float* biN = (d < 11) ? ln1_b + (size_t)(d + 1) * 384 : nullptr;
    k_gemm_nfull<3><<<196, 256, 0, stream>>>(hid, w2T, 1536, b2 + (size_t)d * 384, h, h,
                                             scN, biN, z);
  }

  // transpose head_w (384,1000) -> hwT (1000,384) fp32 (hid buffer is free now)
  k_tcastf<<<dim3(32, 12), tb, 0, stream>>>(head_w, hwT, 384, 1000);

  k_lnpool<<<32, 256, 0, stream>>>(h, lnf_s, lnf_b, pooled);
  k_head<<<8000, 256, 0, stream>>>(pooled, hwT, head_b, out);
}

// Round 15
// 1314.228 us; speedup vs baseline: 1.1748x; 1.1748x over previous
//
#include <hip/hip_runtime.h>
#include <cstdint>
#include <cstddef>

#define DEV static __device__ __forceinline__

typedef unsigned short u16;
typedef unsigned int u32;
typedef __attribute__((ext_vector_type(8))) short short8;
typedef __attribute__((ext_vector_type(8))) __bf16 bf16x8;
typedef __attribute__((ext_vector_type(4))) float f32x4;

constexpr size_t PER_D = 1474560;

DEV u16 f2bf(float f) {
  u32 u = __builtin_bit_cast(u32, f);
  u32 r = (u + 0x7fffu + ((u >> 16) & 1u)) >> 16;
  return (u16)r;
}
DEV float bf2f(u16 h) { u32 u = ((u32)h) << 16; return __builtin_bit_cast(float, u); }
DEV u32 pack2(float a, float b) { return (u32)f2bf(a) | ((u32)f2bf(b) << 16); }

// async global->LDS, 16B per lane; lds base must be wave-uniform (dest = base + lane*16)
DEV void ld_lds16(const u16* g, u16* l) {
  __builtin_amdgcn_global_load_lds((const __attribute__((address_space(1))) void*)g,
                                   (__attribute__((address_space(3))) void*)l, 16, 0, 0);
}

// ---------------- all weight transposes+casts in ONE dispatch ----------------
__global__ __launch_bounds__(256) void k_tcast_all(const float* __restrict__ pw, const float* __restrict__ wi,
                                                   const float* __restrict__ wg, const float* __restrict__ w1,
                                                   const float* __restrict__ w2, u16* __restrict__ patchT,
                                                   u16* __restrict__ ugT0, u16* __restrict__ w1T0,
                                                   u16* __restrict__ w2T0) {
  __shared__ float tl[32][33];
  int g = blockIdx.x;
  const float* src; u16* dst; int K, N, bx, by;
  if (g < 288) {                       // patch_w (768,384)
    src = pw; dst = patchT; K = 768; N = 384; bx = g % 12; by = g / 12;
  } else if (g < 288 + 1728) {         // w_in (12,384,384)
    int l = g - 288, z = l / 144, r = l - z * 144;
    bx = r % 12; by = r / 12; K = 384; N = 384;
    src = wi + (size_t)z * 147456; dst = ugT0 + (size_t)z * PER_D;
  } else if (g < 288 + 3456) {         // w_g (12,384,384)
    int l = g - 288 - 1728, z = l / 144, r = l - z * 144;
    bx = r % 12; by = r / 12; K = 384; N = 384;
    src = wg + (size_t)z * 147456; dst = ugT0 + (size_t)z * PER_D + 147456;
  } else if (g < 288 + 3456 + 6912) {  // w1 (12,384,1536)
    int l = g - 288 - 3456, z = l / 576, r = l - z * 576;
    bx = r % 48; by = r / 48; K = 384; N = 1536;
    src = w1 + (size_t)z * 589824; dst = w1T0 + (size_t)z * PER_D;
  } else {                             // w2 (12,1536,384)
    int l = g - 288 - 3456 - 6912, z = l / 576, r = l - z * 576;
    bx = r % 12; by = r / 12; K = 1536; N = 384;
    src = w2 + (size_t)z * 589824; dst = w2T0 + (size_t)z * PER_D;
  }
  int tx = threadIdx.x, ty = threadIdx.y;
  int n0 = bx * 32, k0 = by * 32;
#pragma unroll
  for (int i = 0; i < 4; ++i)
    tl[ty + i * 8][tx] = src[(size_t)(k0 + ty + i * 8) * N + n0 + tx];
  __syncthreads();
#pragma unroll
  for (int i = 0; i < 4; ++i)
    dst[(size_t)(n0 + ty + i * 8) * K + k0 + tx] = f2bf(tl[tx][ty + i * 8]);
}

// ---------------- fp32 transpose with N-guard: src (K,N) -> dst (N,K); K % 32 == 0 ----------------
__global__ __launch_bounds__(256) void k_tcastf(const float* __restrict__ src, float* __restrict__ dst,
                                                int K, int N) {
  __shared__ float tl[32][33];
  int tx = threadIdx.x, ty = threadIdx.y;
  int n0 = blockIdx.x * 32, k0 = blockIdx.y * 32;
#pragma unroll
  for (int i = 0; i < 4; ++i)
    if (n0 + tx < N) tl[ty + i * 8][tx] = src[(size_t)(k0 + ty + i * 8) * N + n0 + tx];
  __syncthreads();
#pragma unroll
  for (int i = 0; i < 4; ++i)
    if (n0 + ty + i * 8 < N) dst[(size_t)(n0 + ty + i * 8) * K + k0 + tx] = tl[tx][ty + i * 8];
}

// ---------------- patch extraction: x (B,224,224,3) -> pA bf16 (6272,768); 8 elems/thread ----------------
__global__ __launch_bounds__(256) void k_patch_extract(const float* __restrict__ x, u16* __restrict__ pA) {
  int idx = (blockIdx.x * 256 + threadIdx.x) * 8;
  int token = idx / 768, kk = idx - token * 768;
  int b = token / 196, t = token - b * 196;
  int gy = t / 14, gx = t - gy * 14;
  int py = kk / 48, rem = kk - py * 48;
  int px = rem / 3, ch = rem - px * 3;
  size_t s = ((size_t)(b * 224 + gy * 16 + py) * 224 + (gx * 16 + px)) * 3 + ch;
  union { short8 s8; u16 u[8]; } pk;
#pragma unroll
  for (int j = 0; j < 8; ++j) pk.u[j] = f2bf(x[s + j]);
  *(short8*)(pA + idx) = pk.s8;
}

// ---------------- LayerNorm: h fp32 (6272,384) -> z bf16; wave/token, lane-contiguous ----------------
__global__ __launch_bounds__(256) void k_ln(const float* __restrict__ h, u16* __restrict__ z,
                                            const float* __restrict__ sc, const float* __restrict__ bi) {
  int wave = threadIdx.x >> 6, lane = threadIdx.x & 63;
  int token = blockIdx.x * 4 + wave;
  const float* hp = h + (size_t)token * 384 + lane * 6;
  float2 v0 = *(const float2*)hp;
  float2 v1 = *(const float2*)(hp + 2);
  float2 v2 = *(const float2*)(hp + 4);
  float sum = v0.x + v0.y + v1.x + v1.y + v2.x + v2.y;
  float sq = v0.x * v0.x + v0.y * v0.y + v1.x * v1.x + v1.y * v1.y + v2.x * v2.x + v2.y * v2.y;
#pragma unroll
  for (int o = 1; o < 64; o <<= 1) { sum += __shfl_xor(sum, o); sq += __shfl_xor(sq, o); }
  float mean = sum * (1.f / 384.f);
  float var = sq * (1.f / 384.f) - mean * mean;
  float rstd = rsqrtf(var + 1e-6f);
  const float* scp = sc + lane * 6;
  const float* bip = bi + lane * 6;
  float2 s0 = *(const float2*)scp, s1 = *(const float2*)(scp + 2), s2 = *(const float2*)(scp + 4);
  float2 b0 = *(const float2*)bip, b1 = *(const float2*)(bip + 2), b2 = *(const float2*)(bip + 4);
  u16* zp = z + (size_t)token * 384 + lane * 6;
  *(u32*)(zp)     = pack2((v0.x - mean) * rstd * s0.x + b0.x, (v0.y - mean) * rstd * s0.y + b0.y);
  *(u32*)(zp + 2) = pack2((v1.x - mean) * rstd * s1.x + b1.x, (v1.y - mean) * rstd * s1.y + b1.y);
  *(u32*)(zp + 4) = pack2((v2.x - mean) * rstd * s2.x + b2.x, (v2.y - mean) * rstd * s2.y + b2.y);
}

// ---------------- GEMM: C = A(M,K)bf16 * BT(N,K)bf16, 64xTN tile, 4 waves ----------------
// r10-proven two-barrier K-loop; PANELS 32-wide panels per iter (BK = PANELS*32).
// TN=128: wave=32x64 (r8-verified); TN=64: wave=32x32, half B-stage per block, 2x blocks
// (TLP play for the K=384 shapes; barrier count per block unchanged at K/BK).
// xor-swizzled LDS slots (r8-verified, conflict-free).
// MODE 0: out0 fp32 = acc + bias0[n] + res[(m%196)*384+n]          (patch embed + pos)
// MODE 1: n<384 -> outb = bf16(acc+bias0[n]); else outb2 = bf16(sigmoid(acc+bias1[n-384]))  (u,g)
// MODE 2: outb bf16 = gelu_tanh(acc + bias0[n]), row stride N      (MLP1)
// MODE 3: out0 fp32 = res[m*384+n] + acc + bias0[n]                (MLP2 + residual)
template <int MODE, int PANELS, int TN>
__global__ __launch_bounds__(256) void k_gemm(const u16* __restrict__ A, const u16* __restrict__ BT,
                                              int K, int N,
                                              const float* __restrict__ bias0, const float* __restrict__ bias1,
                                              float* __restrict__ out0, u16* __restrict__ outb,
                                              u16* __restrict__ outb2, const float* __restrict__ res) {
  constexpr int NJ = TN / 32;   // B fragments per wave
  constexpr int BST = TN / 64;  // B staging chunks (64 rows each)
  __shared__ alignas(16) u16 As[PANELS][64 * 32];
  __shared__ alignas(16) u16 Bs[PANELS][TN * 32];
  const int tid = threadIdx.x;
  const int tm = blockIdx.y * 64, tn = blockIdx.x * TN;
  const int lane = tid & 63, wave = tid >> 6;
  const int wy = (wave >> 1) * 32, wx = (wave & 1) * (TN / 2);
  const int quad = lane >> 4, r15 = lane & 15;
  const int swz = (quad ^ ((r15 >> 1) & 3)) * 8;
  const int rowS = tid >> 2;
  const int colS = (((tid & 3) ^ ((rowS >> 1) & 3))) * 8;
  const u16* Ab = A + (size_t)(tm + rowS) * K + colS;
  const u16* Bb = BT + (size_t)(tn + rowS) * K + colS;
  f32x4 acc[2][NJ] = {};
  for (int k0 = 0; k0 < K; k0 += PANELS * 32) {
#pragma unroll
    for (int p = 0; p < PANELS; ++p) {
      ld_lds16(Ab + k0 + p * 32, &As[p][wave * 512]);
#pragma unroll
      for (int st = 0; st < BST; ++st)
        ld_lds16(Bb + (size_t)st * 64 * K + k0 + p * 32, &Bs[p][wave * 512 + st * 2048]);
    }
    __syncthreads();
#pragma unroll
    for (int p = 0; p < PANELS; ++p) {
      bf16x8 af[2], bw[NJ];
#pragma unroll
      for (int i = 0; i < 2; ++i) af[i] = *(const bf16x8*)&As[p][(wy + i * 16 + r15) * 32 + swz];
#pragma unroll
      for (int j = 0; j < NJ; ++j) bw[j] = *(const bf16x8*)&Bs[p][(wx + j * 16 + r15) * 32 + swz];
#pragma unroll
      for (int i = 0; i < 2; ++i)
#pragma unroll
        for (int j = 0; j < NJ; ++j)
          acc[i][j] = __builtin_amdgcn_mfma_f32_16x16x32_bf16(af[i], bw[j], acc[i][j], 0, 0, 0);
    }
    __syncthreads();
  }
#pragma unroll
  for (int i = 0; i < 2; ++i) {
#pragma unroll
    for (int j = 0; j < NJ; ++j) {
#pragma unroll
      for (int rr = 0; rr < 4; ++rr) {
        int m = tm + wy + i * 16 + quad * 4 + rr;
        int n = tn + wx + j * 16 + r15;
        float v = acc[i][j][rr];
        if (MODE == 0) {
          v += bias0[n] + res[(size_t)(m % 196) * 384 + n];
          out0[(size_t)m * N + n] = v;
        } else if (MODE == 1) {
          if (n < 384) {
            outb[(size_t)m * 384 + n] = f2bf(v + bias0[n]);
          } else {
            float t = v + bias1[n - 384];
            outb2[(size_t)m * 384 + (n - 384)] = f2bf(1.f / (1.f + expf(-t)));
          }
        } else if (MODE == 2) {
          v += bias0[n];
          float gl = 0.5f * v * (1.f + tanhf(0.7978845608028654f * (v + 0.044715f * v * v * v)));
          outb[(size_t)m * N + n] = f2bf(gl);
        } else {
          out0[(size_t)m * 384 + n] = res[(size_t)m * 384 + n] + v + bias0[n];
        }
      }
    }
  }
}

// ---------------- gated depthwise-conv recurrence, T=8; ping-pong LDS, 9 barriers ----------------
__global__ __launch_bounds__(256) void k_recur(float* __restrict__ h, const u16* __restrict__ ubuf,
                                               const u16* __restrict__ gbuf, const float* __restrict__ kd) {
  __shared__ float sb[2][16 * 16 * 8];  // [buf][y+1][x+1][c], zero halo, 16 KB
  const int tid = threadIdx.x;
  const int b = blockIdx.x, cg = blockIdx.y;
  const int c = tid & 7, pg = tid >> 3;  // pg in [0,32)
  const int cfull = cg * 8 + c;
  float kw[9];
#pragma unroll
  for (int q = 0; q < 9; ++q) kw[q] = kd[q * 384 + cfull];
  float gr[7], ur[7], sr[7];
  int yy[7], xx[7];
#pragma unroll
  for (int kk = 0; kk < 7; ++kk) {
    int p = pg + kk * 32;
    bool ok = p < 196;
    size_t a = (size_t)(b * 196 + (ok ? p : 0)) * 384 + cfull;
    gr[kk] = ok ? bf2f(gbuf[a]) : 0.f;
    ur[kk] = ok ? bf2f(ubuf[a]) : 0.f;
    sr[kk] = 0.f;
    yy[kk] = p / 14; xx[kk] = p - yy[kk] * 14;
  }
  for (int i = tid; i < 2 * 16 * 16 * 8; i += 256) ((float*)sb)[i] = 0.f;
  __syncthreads();
#pragma unroll
  for (int kk = 0; kk < 7; ++kk) {
    int p = pg + kk * 32;
    if (p < 196) {
      sr[kk] = (1.f - gr[kk]) * ur[kk];
      sb[0][((yy[kk] + 1) * 16 + (xx[kk] + 1)) * 8 + c] = sr[kk];
    }
  }
  __syncthreads();
  for (int t = 1; t < 8; ++t) {
    const float* rd = sb[(t - 1) & 1];
    float* wr = sb[t & 1];
#pragma unroll
    for (int kk = 0; kk < 7; ++kk) {
      int p = pg + kk * 32;
      if (p < 196) {
        int base = (yy[kk] * 16 + xx[kk]) * 8 + c;
        float conv = 0.f;
#pragma unroll
        for (int dy = 0; dy < 3; ++dy)
#pragma unroll
          for (int dx = 0; dx < 3; ++dx)
            conv += kw[dy * 3 + dx] * rd[base + (dy * 16 + dx) * 8];
        sr[kk] = gr[kk] * conv + (1.f - gr[kk]) * ur[kk];
        wr[((yy[kk] + 1) * 16 + (xx[kk] + 1)) * 8 + c] = sr[kk];
      }
    }
    __syncthreads();
  }
#pragma unroll
  for (int kk = 0; kk < 7; ++kk) {
    int p = pg + kk * 32;
    if (p < 196) {
      size_t a = (size_t)(b * 196 + p) * 384 + cfull;
      h[a] += sr[kk];
    }
  }
}

// ---------------- fused final LN + spatial max-pool: pooled(32,384) fp32 ----------------
__global__ __launch_bounds__(256) void k_lnpool(const float* __restrict__ h, const float* __restrict__ sc,
                                                const float* __restrict__ bi, float* __restrict__ pooled) {
  __shared__ float red[4][384];
  const int b = blockIdx.x;
  const int wave = threadIdx.x >> 6, lane = threadIdx.x & 63;
  const float* scp = sc + lane * 6;
  const float* bip = bi + lane * 6;
  float2 s0 = *(const float2*)scp, s1 = *(const float2*)(scp + 2), s2 = *(const float2*)(scp + 4);
  float2 b0 = *(const float2*)bip, b1 = *(const float2*)(bip + 2), b2 = *(const float2*)(bip + 4);
  float mx[6] = {-3.4e38f, -3.4e38f, -3.4e38f, -3.4e38f, -3.4e38f, -3.4e38f};
  for (int i = 0; i < 49; ++i) {
    int t = wave + 4 * i;
    const float* hp = h + (size_t)(b * 196 + t) * 384 + lane * 6;
    float2 v0 = *(const float2*)hp;
    float2 v1 = *(const float2*)(hp + 2);
    float2 v2 = *(const float2*)(hp + 4);
    float sum = v0.x + v0.y + v1.x + v1.y + v2.x + v2.y;
    float sq = v0.x * v0.x + v0.y * v0.y + v1.x * v1.x + v1.y * v1.y + v2.x * v2.x + v2.y * v2.y;
#pragma unroll
    for (int o = 1; o < 64; o <<= 1) { sum += __shfl_xor(sum, o); sq += __shfl_xor(sq, o); }
    float mean = sum * (1.f / 384.f);
    float var = sq * (1.f / 384.f) - mean * mean;
    float rstd = rsqrtf(var + 1e-6f);
    mx[0] = fmaxf(mx[0], (v0.x - mean) * rstd * s0.x + b0.x);
    mx[1] = fmaxf(mx[1], (v0.y - mean) * rstd * s0.y + b0.y);
    mx[2] = fmaxf(mx[2], (v1.x - mean) * rstd * s1.x + b1.x);
    mx[3] = fmaxf(mx[3], (v1.y - mean) * rstd * s1.y + b1.y);
    mx[4] = fmaxf(mx[4], (v2.x - mean) * rstd * s2.x + b2.x);
    mx[5] = fmaxf(mx[5], (v2.y - mean) * rstd * s2.y + b2.y);
  }
#pragma unroll
  for (int j = 0; j < 6; ++j) red[wave][lane * 6 + j] = mx[j];
  __syncthreads();
  if (wave == 0) {
#pragma unroll
    for (int j = 0; j < 6; ++j) {
      int cc = lane * 6 + j;
      pooled[b * 384 + cc] = fmaxf(fmaxf(red[0][cc], red[1][cc]), fmaxf(red[2][cc], red[3][cc]));
    }
  }
}

// ---------------- head GEMV: wave per (b,n); hwT is (1000,384) fp32 ----------------
__global__ __launch_bounds__(256) void k_head(const float* __restrict__ pooled, const float* __restrict__ hwT,
                                              const float* __restrict__ hb, float* __restrict__ out) {
  int w = (blockIdx.x * 256 + threadIdx.x) >> 6;  // 0..31999
  int lane = threadIdx.x & 63;
  int b = w / 1000, n = w - b * 1000;
  const float* pp = pooled + b * 384 + lane;
  const float* wp = hwT + (size_t)n * 384 + lane;
  float acc = 0.f;
#pragma unroll
  for (int j = 0; j < 6; ++j) acc += pp[j * 64] * wp[j * 64];
#pragma unroll
  for (int o = 1; o < 64; o <<= 1) acc += __shfl_xor(acc, o);
  if (lane == 0) out[w] = acc + hb[n];
}

extern "C" void kernel_launch(void* const* d_in, const int* in_sizes, int n_in,
                              void* d_out, int out_size, void* d_ws, size_t ws_size,
                              hipStream_t stream) {
  const float* x       = (const float*)d_in[0];
  const float* patch_w = (const float*)d_in[1];
  const float* patch_b = (const float*)d_in[2];
  const float* pos     = (const float*)d_in[3];
  const float* ln1_s   = (const float*)d_in[4];
  const float* ln1_b   = (const float*)d_in[5];
  const float* w_in    = (const float*)d_in[6];
  const float* b_in    = (const float*)d_in[7];
  const float* w_g     = (const float*)d_in[8];
  const float* b_g     = (const float*)d_in[9];
  const float* k_dw    = (const float*)d_in[10];
  const float* ln2_s   = (const float*)d_in[11];
  const float* ln2_b   = (const float*)d_in[12];
  const float* w1      = (const float*)d_in[13];
  const float* b1      = (const float*)d_in[14];
  const float* w2      = (const float*)d_in[15];
  const float* b2      = (const float*)d_in[16];
  const float* lnf_s   = (const float*)d_in[17];
  const float* lnf_b   = (const float*)d_in[18];
  const float* head_w  = (const float*)d_in[19];
  const float* head_b  = (const float*)d_in[20];
  float* out = (float*)d_out;

  const size_t M = 6272;
  const size_t SZ_TOK = M * 384;               // 2408448
  const size_t SZ_HID = M * 1536;              // 9633792
  const size_t WT_ELEMS = 17989632;            // patchT + 12*(ugT + w1T + w2T)
  const size_t NEED = SZ_TOK * 4 + SZ_TOK * 2 * 3 + SZ_HID * 2 + WT_ELEMS * 2;
  if (ws_size < NEED) return;

  char* ws = (char*)d_ws;
  float* h = (float*)ws;   ws += SZ_TOK * 4;
  u16* ub  = (u16*)ws;     ws += SZ_TOK * 2;
  u16* gb  = (u16*)ws;     ws += SZ_TOK * 2;
  u16* z   = (u16*)ws;     ws += SZ_TOK * 2;
  u16* hid = (u16*)ws;     ws += SZ_HID * 2;
  u16* pA  = hid;          // alias: patch A-matrix (M*768) fits in hid (M*1536), used before hid
  u16* wT  = (u16*)ws;
  float* pooled = (float*)ub;  // reuse ub at the end (free after last recur)
  float* hwT = (float*)hid;    // reuse hid at the end (free after last gemm3)

  // wT layout (elems): patchT[294912]; per d: WiT[147456] WgT[147456] w1T[589824] w2T[589824]
  u16* patchT = wT;
  u16* ugT0 = wT + 294912;
  u16* w1T0 = wT + 294912 + 294912;
  u16* w2T0 = wT + 294912 + 294912 + 589824;

  dim3 tb(32, 8);
  k_tcast_all<<<17568, tb, 0, stream>>>(patch_w, w_in, w_g, w1, w2, patchT, ugT0, w1T0, w2T0);

  k_patch_extract<<<2352, 256, 0, stream>>>(x, pA);

  // patch embed GEMM: h = pA @ patch_w + patch_b + pos  (64x128 tiles: 3x98, BK=128)
  k_gemm<0, 4, 128><<<dim3(3, 98), 256, 0, stream>>>(pA, patchT, 768, 384, patch_b, nullptr,
                                                     h, nullptr, nullptr, pos);

  for (int d = 0; d < 12; ++d) {
    const u16* ugT = ugT0 + (size_t)d * PER_D;
    const u16* w1T = w1T0 + (size_t)d * PER_D;
    const u16* w2T = w2T0 + (size_t)d * PER_D;
    k_ln<<<1568, 256, 0, stream>>>(h, z, ln1_s + (size_t)d * 384, ln1_b + (size_t)d * 384);
    // u,g: TN=64 -> 12x98 = 1176 blocks (was 588)
    k_gemm<1, 2, 64><<<dim3(12, 98), 256, 0, stream>>>(z, ugT, 384, 768, b_in + (size_t)d * 384,
                                                       b_g + (size_t)d * 384, nullptr, ub, gb, nullptr);
    k_recur<<<dim3(32, 48), 256, 0, stream>>>(h, ub, gb, k_dw + (size_t)d * 3456);
    k_ln<<<1568, 256, 0, stream>>>(h, z, ln2_s + (size_t)d * 384, ln2_b + (size_t)d * 384);
    // MLP1: TN=64 -> 24x98 = 2352 blocks (was 1176)
    k_gemm<2, 2, 64><<<dim3(24, 98), 256, 0, stream>>>(z, w1T, 384, 1536, b1 + (size_t)d * 1536,
                                                       nullptr, nullptr, hid, nullptr, nullptr);
    k_gemm<3, 4, 128><<<dim3(3, 98), 256, 0, stream>>>(hid, w2T, 1536, 384, b2 + (size_t)d * 384,
                                                       nullptr, h, nullptr, nullptr, h);
  }

  // transpose head_w (384,1000) -> hwT (1000,384) fp32 (hid buffer is free now)
  k_tcastf<<<dim3(32, 12), tb, 0, stream>>>(head_w, hwT, 384, 1000);

  k_lnpool<<<32, 256, 0, stream>>>(h, lnf_s, lnf_b, pooled);
  k_head<<<8000, 256, 0, stream>>>(pooled, hwT, head_b, out);
}